// Round 5
// baseline (731.286 us; speedup 1.0000x reference)
//
#include <hip/hip_runtime.h>
#include <hip/hip_bf16.h>

#define B_ 128
#define T_ 512
#define C_ 1024

typedef __attribute__((ext_vector_type(8))) short short8;
typedef __attribute__((ext_vector_type(4))) float f32x4;

__device__ __forceinline__ unsigned short f2bf(float f){
  unsigned u; __builtin_memcpy(&u, &f, 4);
  u += 0x7FFFu + ((u >> 16) & 1u);          // RNE
  return (unsigned short)(u >> 16);
}

// ---- async global->LDS 16B (LDS dest: wave-uniform base + lane*16)
typedef __attribute__((address_space(3))) unsigned lds_u32_t;
typedef __attribute__((address_space(1))) unsigned glb_u32_t;
__device__ __forceinline__ void gload16(const void* g, void* l){
  __builtin_amdgcn_global_load_lds((const glb_u32_t*)g, (lds_u32_t*)l, 16, 0, 0);
}

// ---------------- cast f32 -> bf16 (vectorized) ----------------
__global__ void cast_f32_bf16(const float* __restrict__ in, unsigned short* __restrict__ out, long n){
  long i = (long)blockIdx.x * blockDim.x + threadIdx.x;
  long stride = (long)gridDim.x * blockDim.x;
  for (long j = i * 4; j < n; j += stride * 4){
    float4 v = *(const float4*)(in + j);
    ushort4 o; o.x = f2bf(v.x); o.y = f2bf(v.y); o.z = f2bf(v.z); o.w = f2bf(v.w);
    *(ushort4*)(out + j) = o;
  }
}

// ---------------- transpose-cast W_proj (e,c) -> WpT (c,e) bf16 ----------------
__global__ void transpose_cast(const float* __restrict__ in, unsigned short* __restrict__ out){
  __shared__ float tile[32][33];
  int c0 = blockIdx.x * 32, e0 = blockIdx.y * 32;
  int tx = threadIdx.x, ty = threadIdx.y;     // (32,8)
  for (int r = 0; r < 32; r += 8)
    tile[ty + r][tx] = in[(size_t)(e0 + ty + r) * C_ + c0 + tx];
  __syncthreads();
  for (int r = 0; r < 32; r += 8)
    out[(size_t)(c0 + ty + r) * C_ + e0 + tx] = f2bf(tile[tx][ty + r]);
}

// ---------------- small bf16 GEMM (weight fuse), m97-style 128x128 ----------------
__global__ __launch_bounds__(256) void gemm_bt_bf16(
    const unsigned short* __restrict__ A,   // M x K
    const unsigned short* __restrict__ Bt,  // N x K
    unsigned short* __restrict__ Cc,        // M x N
    int M, int N, int K)
{
  __shared__ short As[128 * 32];
  __shared__ short Bs[128 * 32];
  const int tid  = threadIdx.x;
  const int lane = tid & 63;
  const int wave = tid >> 6;
  const int wr = wave >> 1, wc = wave & 1;
  const int lr = lane & 15, kg = lane >> 4;
  const int m0 = blockIdx.x * 128;
  const int n0 = blockIdx.y * 128;

  f32x4 acc[4][4];
  #pragma unroll
  for (int mi = 0; mi < 4; mi++)
    #pragma unroll
    for (int ni = 0; ni < 4; ni++)
      acc[mi][ni] = (f32x4){0.f, 0.f, 0.f, 0.f};

  const int r1 = tid >> 2, ch1 = tid & 3;
  char* abase = (char*)As + (tid & ~63) * 16;
  char* bbase = (char*)Bs + (tid & ~63) * 16;

  for (int k0 = 0; k0 < K; k0 += 32){
    __syncthreads();
    gload16(A  + (size_t)(m0 + r1)      * K + k0 + ch1 * 8, abase);
    gload16(A  + (size_t)(m0 + 64 + r1) * K + k0 + ch1 * 8, abase + 4096);
    gload16(Bt + (size_t)(n0 + r1)      * K + k0 + ch1 * 8, bbase);
    gload16(Bt + (size_t)(n0 + 64 + r1) * K + k0 + ch1 * 8, bbase + 4096);
    __syncthreads();

    short8 af[4], bfr[4];
    #pragma unroll
    for (int mi = 0; mi < 4; mi++)
      af[mi] = *(const short8*)&As[(wr * 64 + mi * 16 + lr) * 32 + kg * 8];
    #pragma unroll
    for (int ni = 0; ni < 4; ni++)
      bfr[ni] = *(const short8*)&Bs[(wc * 64 + ni * 16 + lr) * 32 + kg * 8];
    #pragma unroll
    for (int mi = 0; mi < 4; mi++)
      #pragma unroll
      for (int ni = 0; ni < 4; ni++)
        acc[mi][ni] = __builtin_amdgcn_mfma_f32_16x16x32_bf16(af[mi], bfr[ni], acc[mi][ni], 0, 0, 0);
  }

  #pragma unroll
  for (int mi = 0; mi < 4; mi++)
    #pragma unroll
    for (int ni = 0; ni < 4; ni++){
      int n = n0 + wc * 64 + ni * 16 + lr;
      int mb = m0 + wr * 64 + mi * 16 + kg * 4;
      #pragma unroll
      for (int j = 0; j < 4; j++)
        Cc[(size_t)(mb + j) * N + n] = f2bf(acc[mi][ni][j]);
    }
}

// ================= 256x256 8-phase GEMM (T2+T3+T4+T5), writes vt (C,B,T) =================
// A: (65536 x 1024) bf16, Bt: (1024 x 1024) bf16, K=1024 fixed.
// LDS layout: A[slot][kh][256][32] at 0, B[slot][kh][256][32] at 65536. Rows 64B.
// Swizzle involution on in-unit byte offset: off ^= ((off>>7)&3)<<4  (2-way free reads).
#define SWZ(x) ((x) ^ ((((x) >> 7) & 3) << 4))

#define STAGE_A(kt, kh) { \
  int d_ = wv * 1024 + ln * 16; int o_ = SWZ(d_); \
  gload16(Ag + (size_t)(m0 + (o_ >> 6)) * 1024 + (kt) * 64 + (kh) * 32 + ((o_ >> 4) & 3) * 8, \
          ldsc + ((kt) & 1) * 32768 + (kh) * 16384 + wv * 1024); \
  d_ += 8192; o_ = SWZ(d_); \
  gload16(Ag + (size_t)(m0 + (o_ >> 6)) * 1024 + (kt) * 64 + (kh) * 32 + ((o_ >> 4) & 3) * 8, \
          ldsc + ((kt) & 1) * 32768 + (kh) * 16384 + 8192 + wv * 1024); }

#define STAGE_B(kt, kh) { \
  int d_ = wv * 1024 + ln * 16; int o_ = SWZ(d_); \
  gload16(Bg + (size_t)(n0 + (o_ >> 6)) * 1024 + (kt) * 64 + (kh) * 32 + ((o_ >> 4) & 3) * 8, \
          ldsc + 65536 + ((kt) & 1) * 32768 + (kh) * 16384 + wv * 1024); \
  d_ += 8192; o_ = SWZ(d_); \
  gload16(Bg + (size_t)(n0 + (o_ >> 6)) * 1024 + (kt) * 64 + (kh) * 32 + ((o_ >> 4) & 3) * 8, \
          ldsc + 65536 + ((kt) & 1) * 32768 + (kh) * 16384 + 8192 + wv * 1024); }

// counted waits: NO "memory" clobber (a memory-clobbering asm forces the backend
// to conservatively drain vmcnt->0 each phase, killing T4). sched_barrier(0) on
// both sides pins the DMA issues / waits so the counted-N semantics stay exact.
#define VMCNT_PIN(N) { \
  __builtin_amdgcn_sched_barrier(0); \
  asm volatile("s_waitcnt vmcnt(" #N ")"); \
  __builtin_amdgcn_sched_barrier(0); }

// phase: ds-read frags || stage one unit -> barrier -> lgkm(0) -> 16 MFMA -> [vmcnt] -> barrier
#define PHASE(S, KH, NH, STG, CK) { \
  if ((NH) == 0) { \
    _Pragma("unroll") for (int mi = 0; mi < 8; mi++){ \
      int off_ = (S) * 32768 + (KH) * 16384 + (wr * 128 + mi * 16 + lr) * 64 + kg * 16; \
      a[mi] = *(const short8*)(ldsc + SWZ(off_)); } } \
  { _Pragma("unroll") for (int nn = 0; nn < 2; nn++){ \
      int off_ = 65536 + (S) * 32768 + (KH) * 16384 + (wc * 64 + ((NH) * 2 + nn) * 16 + lr) * 64 + kg * 16; \
      b[nn] = *(const short8*)(ldsc + SWZ(off_)); } } \
  STG; \
  __builtin_amdgcn_sched_barrier(0); \
  __builtin_amdgcn_s_barrier(); \
  asm volatile("s_waitcnt lgkmcnt(0)"); \
  __builtin_amdgcn_sched_barrier(0); \
  __builtin_amdgcn_s_setprio(1); \
  _Pragma("unroll") for (int mi = 0; mi < 8; mi++){ \
    acc[mi][(NH)*2+0] = __builtin_amdgcn_mfma_f32_16x16x32_bf16(a[mi], b[0], acc[mi][(NH)*2+0], 0, 0, 0); \
    acc[mi][(NH)*2+1] = __builtin_amdgcn_mfma_f32_16x16x32_bf16(a[mi], b[1], acc[mi][(NH)*2+1], 0, 0, 0); } \
  __builtin_amdgcn_s_setprio(0); \
  CK; \
  __builtin_amdgcn_s_barrier(); }

__global__ __launch_bounds__(512, 2) void gemm256_vt(
    const unsigned short* __restrict__ Ag,  // 65536 x 1024
    const unsigned short* __restrict__ Bg,  // 1024 x 1024 (Bt)
    unsigned short* __restrict__ vt)        // (C, B, T)
{
  extern __shared__ char ldsc[];            // 131072 B
  const int tid = threadIdx.x;
  const int ln  = tid & 63;
  const int wv  = tid >> 6;                 // 8 waves
  const int wr  = wv >> 2;                  // 2 M-waves (128 rows each)
  const int wc  = wv & 3;                   // 4 N-waves (64 cols each)
  const int lr  = ln & 15, kg = ln >> 4;
  const int m0  = blockIdx.y * 256;
  const int n0  = blockIdx.x * 256;

  // prologue: stage tile0 fully + tile1 {A0,B0,A1}; leave B1(1) for iter0-p1
  STAGE_A(0, 0); STAGE_B(0, 0); STAGE_A(0, 1); STAGE_B(0, 1);
  STAGE_A(1, 0); STAGE_B(1, 0); STAGE_A(1, 1);

  f32x4 acc[8][4];
  #pragma unroll
  for (int mi = 0; mi < 8; mi++)
    #pragma unroll
    for (int ni = 0; ni < 4; ni++)
      acc[mi][ni] = (f32x4){0.f, 0.f, 0.f, 0.f};

  VMCNT_PIN(6);                              // tile0's 8 loads landed
  __builtin_amdgcn_s_barrier();

  short8 a[8], b[2];

  #pragma unroll 1
  for (int it = 0; it < 8; ++it){
    const int e = 2 * it + 2, od = 2 * it + 3;
    // tiles t0=2it (slot0) phases 1-4, t1=2it+1 (slot1) phases 5-8
    PHASE(0, 0, 0, { STAGE_B(2 * it + 1, 1); }, {});
    PHASE(0, 0, 1, { if (it < 7) STAGE_A(e, 0); }, {});
    PHASE(0, 1, 0, { if (it < 7) STAGE_B(e, 0); }, {});
    PHASE(0, 1, 1, { if (it < 7) STAGE_A(e, 1); },
          { if (it == 7) VMCNT_PIN(0) else VMCNT_PIN(6) });
    PHASE(1, 0, 0, { if (it < 7) STAGE_B(e, 1); }, {});
    PHASE(1, 0, 1, { if (it < 7) STAGE_A(od, 0); }, {});
    PHASE(1, 1, 0, { if (it < 7) STAGE_B(od, 0); }, {});
    PHASE(1, 1, 1, { if (it < 7) STAGE_A(od, 1); },
          { if (it < 7) VMCNT_PIN(6) });
  }

  // epilogue: vt[(n*B + b)*T + t], m = b*512 + t
  #pragma unroll
  for (int mi = 0; mi < 8; mi++)
    #pragma unroll
    for (int ni = 0; ni < 4; ni++){
      int n  = n0 + wc * 64 + ni * 16 + lr;
      int mb = m0 + wr * 128 + mi * 16 + kg * 4;
      int bb = mb >> 9, t = mb & 511;
      ushort4 o;
      o.x = f2bf(acc[mi][ni][0]); o.y = f2bf(acc[mi][ni][1]);
      o.z = f2bf(acc[mi][ni][2]); o.w = f2bf(acc[mi][ni][3]);
      *(ushort4*)&vt[((size_t)n * B_ + bb) * T_ + t] = o;
    }
}

// ---------------- Toeplitz band table: band[c][d32][i][j] = z_c[32*d32 + i - j] ----------------
__global__ void band_prep(const float* __restrict__ pw, const float* __restrict__ line,
                          unsigned short* __restrict__ band){
  const int c = blockIdx.x, d32 = blockIdx.y;
  const float p = pw[c];
  const float e = 2.0f + 100.0f / (1.0f + expf(-p));
  const int tid = threadIdx.x;
  for (int idx = tid; idx < 1280; idx += 256){
    int i = idx / 40, j = idx - i * 40;
    int k = d32 * 32 + i - j;
    float z = 0.f;
    if (j < 32 && k >= 0 && k < T_){
      float lv = line[k];
      z = (lv > 0.f) ? expf(e * logf(lv)) : 0.f;
    }
    band[((size_t)c * 16 + d32) * 1280 + idx] = f2bf(z);
  }
}

// ---------------- conv via MFMA: per (t-tile, c) block, Y[t][b] = sum_s z[t-s] v[b][s] ----
__global__ __launch_bounds__(256) void conv_mfma(
    const unsigned short* __restrict__ vt,    // (C, B, T) bf16
    const unsigned short* __restrict__ band,  // (C, 16, 32, 40) bf16
    const float* __restrict__ gain,           // (1,1,C)
    unsigned short* __restrict__ Ybf)         // (C, B, T) bf16, gain+relu applied
{
  __shared__ short Bs[128 * 32];      // v tile: 128 b x 32 s
  __shared__ short Ab[16 * 1280];     // up to 16 Toeplitz bands (40KB)
  const int t0  = blockIdx.x << 7;    // 4 t-tiles (fastest -> same-c adjacency)
  const int c   = blockIdx.y;
  const int tid = threadIdx.x, lane = tid & 63, wave = tid >> 6;
  const int wr = wave >> 1, wc = wave & 1, lr = lane & 15, kg = lane >> 4;
  const int K  = t0 + 128;            // causal: s < t0+128
  const int nb = (t0 >> 5) + 4;       // bands d32 = 0..nb-1

  // stage all needed bands once (linear gload16)
  {
    const unsigned short* src = band + (size_t)c * (16 * 1280);
    const int nch = nb * 160;                      // 16B chunks
    for (int q0 = 0; q0 < nch; q0 += 256){
      int q = q0 + tid;
      char* dst = (char*)Ab + q0 * 16 + wave * 1024;   // wave-uniform
      if (q < nch) gload16(src + (size_t)q * 8, dst);
    }
  }

  f32x4 acc[4][4];
  #pragma unroll
  for (int mi = 0; mi < 4; mi++)
    #pragma unroll
    for (int ni = 0; ni < 4; ni++)
      acc[mi][ni] = (f32x4){0.f, 0.f, 0.f, 0.f};

  const int r1 = tid >> 2, ch1 = tid & 3;
  char* bbase = (char*)Bs + (tid & ~63) * 16;
  const size_t vbase = (size_t)c * B_ * T_;

  for (int k0 = 0; k0 < K; k0 += 32){
    __syncthreads();
    gload16(vt + vbase + (size_t)r1 * T_        + k0 + ch1 * 8, bbase);
    gload16(vt + vbase + (size_t)(64 + r1) * T_ + k0 + ch1 * 8, bbase + 4096);
    __syncthreads();

    short8 bfr[4];
    #pragma unroll
    for (int ni = 0; ni < 4; ni++)
      bfr[ni] = *(const short8*)&Bs[(wc * 64 + ni * 16 + lr) * 32 + kg * 8];

    const int dbase = ((t0 - k0) >> 5) + wr * 2;
    #pragma unroll
    for (int mi = 0; mi < 4; mi++){
      const int d32 = dbase + (mi >> 1);         // wave-uniform per mi
      if (d32 >= 0){
        const int i = ((mi & 1) << 4) + lr;      // row within band
        short8 af = *(const short8*)&Ab[d32 * 1280 + i * 40 + kg * 8];
        #pragma unroll
        for (int ni = 0; ni < 4; ni++)
          acc[mi][ni] = __builtin_amdgcn_mfma_f32_16x16x32_bf16(af, bfr[ni], acc[mi][ni], 0, 0, 0);
      }
    }
  }

  const float g = gain[c];
  #pragma unroll
  for (int mi = 0; mi < 4; mi++)
    #pragma unroll
    for (int ni = 0; ni < 4; ni++){
      int t = t0 + wr * 64 + mi * 16 + kg * 4;   // 4 consecutive t (j)
      int b = wc * 64 + ni * 16 + lr;
      ushort4 o;
      o.x = f2bf(fmaxf(acc[mi][ni][0] * g, 0.f));
      o.y = f2bf(fmaxf(acc[mi][ni][1] * g, 0.f));
      o.z = f2bf(fmaxf(acc[mi][ni][2] * g, 0.f));
      o.w = f2bf(fmaxf(acc[mi][ni][3] * g, 0.f));
      *(ushort4*)&Ybf[((size_t)c * B_ + b) * T_ + t] = o;
    }
}

// ---------------- final: (C,B,T) bf16 -> (B,T,C) f32 ----------------
__global__ __launch_bounds__(256) void final_out(const unsigned short* __restrict__ Ybf,
                                                 float* __restrict__ out){
  __shared__ unsigned short tile[64][72];
  const int c0 = blockIdx.x * 64;
  const int t0 = blockIdx.y * 64;
  const int b  = blockIdx.z;
  const int tid = threadIdx.x;
  const int cr = tid >> 4;
  const int t4 = (tid & 15) * 4;
  for (int q = 0; q < 64; q += 16){
    ushort4 u = *(const ushort4*)&Ybf[((size_t)(c0 + cr + q) * B_ + b) * T_ + t0 + t4];
    *(ushort4*)&tile[cr + q][t4] = u;
  }
  __syncthreads();
  const int tr = tid >> 4;
  const int c4 = (tid & 15) * 4;
  for (int q = 0; q < 64; q += 16){
    int t = tr + q;
    float4 o;
    o.x = __uint_as_float((unsigned)tile[c4 + 0][t] << 16);
    o.y = __uint_as_float((unsigned)tile[c4 + 1][t] << 16);
    o.z = __uint_as_float((unsigned)tile[c4 + 2][t] << 16);
    o.w = __uint_as_float((unsigned)tile[c4 + 3][t] << 16);
    *(float4*)&out[((size_t)b * T_ + t0 + t) * C_ + c0 + c4] = o;
  }
}

extern "C" void kernel_launch(void* const* d_in, const int* in_sizes, int n_in,
                              void* d_out, int out_size, void* d_ws, size_t ws_size,
                              hipStream_t stream)
{
  (void)in_sizes; (void)n_in; (void)out_size; (void)ws_size;
  const float* x    = (const float*)d_in[0];
  const float* Wp   = (const float*)d_in[1];
  const float* Wv   = (const float*)d_in[2];
  const float* gain = (const float*)d_in[3];
  const float* pw   = (const float*)d_in[4];
  const float* line = (const float*)d_in[5];
  float* out = (float*)d_out;

  // ws: [Ybf 128MB][WpT 2MB][Wv_bf 2MB][W_f 2MB]
  char* ws = (char*)d_ws;
  unsigned short* Ybf   = (unsigned short*)ws;
  unsigned short* WpT   = (unsigned short*)(ws + 134217728);
  unsigned short* Wv_bf = (unsigned short*)(ws + 134217728 + 2097152);
  unsigned short* W_f   = (unsigned short*)(ws + 134217728 + 2 * 2097152);
  // d_out (256MB f32) reused as scratch with ping-pong lifetimes:
  unsigned short* x_bf  = (unsigned short*)d_out;                    // lower 128MB (dead after GEMM)
  unsigned short* vt    = (unsigned short*)d_out + 67108864;         // upper 128MB (dead after conv)
  unsigned short* bandp = (unsigned short*)d_out;                    // lower 40MB, written AFTER GEMM

  // weights
  cast_f32_bf16<<<256, 256, 0, stream>>>(Wv, Wv_bf, (long)C_ * C_);
  transpose_cast<<<dim3(32, 32), dim3(32, 8), 0, stream>>>(Wp, WpT);
  gemm_bt_bf16<<<dim3(8, 8), 256, 0, stream>>>(Wv_bf, WpT, W_f, C_, C_, C_);
  // x -> bf16
  cast_f32_bf16<<<2048, 256, 0, stream>>>(x, x_bf, (long)B_ * T_ * C_);
  // v = x @ W_f^T, written directly as (C,B,T); 256^2 8-phase kernel
  gemm256_vt<<<dim3(4, 256), 512, 131072, stream>>>(x_bf, W_f, vt);
  // Toeplitz bands (overwrites x_bf region — dead now)
  band_prep<<<dim3(1024, 16), 256, 0, stream>>>(pw, line, bandp);
  // conv + gain + relu -> Ybf (C,B,T)
  conv_mfma<<<dim3(4, 1024), 256, 0, stream>>>(vt, bandp, gain, Ybf);
  // transpose to (B,T,C) f32
  final_out<<<dim3(16, 8, 128), 256, 0, stream>>>(Ybf, out);
}

// Round 6
// 510.385 us; speedup vs baseline: 1.4328x; 1.4328x over previous
//
#include <hip/hip_runtime.h>
#include <hip/hip_bf16.h>

#define B_ 128
#define T_ 512
#define C_ 1024

typedef __attribute__((ext_vector_type(8))) short short8;
typedef __attribute__((ext_vector_type(4))) float f32x4;

__device__ __forceinline__ unsigned short f2bf(float f){
  unsigned u; __builtin_memcpy(&u, &f, 4);
  u += 0x7FFFu + ((u >> 16) & 1u);          // RNE
  return (unsigned short)(u >> 16);
}

// ---- async global->LDS 16B (LDS dest: wave-uniform base + lane*16)
typedef __attribute__((address_space(3))) unsigned lds_u32_t;
typedef __attribute__((address_space(1))) unsigned glb_u32_t;
__device__ __forceinline__ void gload16(const void* g, void* l){
  __builtin_amdgcn_global_load_lds((const glb_u32_t*)g, (lds_u32_t*)l, 16, 0, 0);
}

// ---------------- cast f32 -> bf16 (vectorized) ----------------
__global__ void cast_f32_bf16(const float* __restrict__ in, unsigned short* __restrict__ out, long n){
  long i = (long)blockIdx.x * blockDim.x + threadIdx.x;
  long stride = (long)gridDim.x * blockDim.x;
  for (long j = i * 4; j < n; j += stride * 4){
    float4 v = *(const float4*)(in + j);
    ushort4 o; o.x = f2bf(v.x); o.y = f2bf(v.y); o.z = f2bf(v.z); o.w = f2bf(v.w);
    *(ushort4*)(out + j) = o;
  }
}

// ---------------- transpose-cast W_proj (e,c) -> WpT (c,e) bf16 ----------------
__global__ void transpose_cast(const float* __restrict__ in, unsigned short* __restrict__ out){
  __shared__ float tile[32][33];
  int c0 = blockIdx.x * 32, e0 = blockIdx.y * 32;
  int tx = threadIdx.x, ty = threadIdx.y;     // (32,8)
  for (int r = 0; r < 32; r += 8)
    tile[ty + r][tx] = in[(size_t)(e0 + ty + r) * C_ + c0 + tx];
  __syncthreads();
  for (int r = 0; r < 32; r += 8)
    out[(size_t)(c0 + ty + r) * C_ + e0 + tx] = f2bf(tile[tx][ty + r]);
}

// ---------------- small bf16 GEMM (weight fuse), m97-style 128x128 ----------------
__global__ __launch_bounds__(256) void gemm_bt_bf16(
    const unsigned short* __restrict__ A,   // M x K
    const unsigned short* __restrict__ Bt,  // N x K
    unsigned short* __restrict__ Cc,        // M x N
    int M, int N, int K)
{
  __shared__ short As[128 * 32];
  __shared__ short Bs[128 * 32];
  const int tid  = threadIdx.x;
  const int lane = tid & 63;
  const int wave = tid >> 6;
  const int wr = wave >> 1, wc = wave & 1;
  const int lr = lane & 15, kg = lane >> 4;
  const int m0 = blockIdx.x * 128;
  const int n0 = blockIdx.y * 128;

  f32x4 acc[4][4];
  #pragma unroll
  for (int mi = 0; mi < 4; mi++)
    #pragma unroll
    for (int ni = 0; ni < 4; ni++)
      acc[mi][ni] = (f32x4){0.f, 0.f, 0.f, 0.f};

  const int r1 = tid >> 2, ch1 = tid & 3;
  char* abase = (char*)As + (tid & ~63) * 16;
  char* bbase = (char*)Bs + (tid & ~63) * 16;

  for (int k0 = 0; k0 < K; k0 += 32){
    __syncthreads();
    gload16(A  + (size_t)(m0 + r1)      * K + k0 + ch1 * 8, abase);
    gload16(A  + (size_t)(m0 + 64 + r1) * K + k0 + ch1 * 8, abase + 4096);
    gload16(Bt + (size_t)(n0 + r1)      * K + k0 + ch1 * 8, bbase);
    gload16(Bt + (size_t)(n0 + 64 + r1) * K + k0 + ch1 * 8, bbase + 4096);
    __syncthreads();

    short8 af[4], bfr[4];
    #pragma unroll
    for (int mi = 0; mi < 4; mi++)
      af[mi] = *(const short8*)&As[(wr * 64 + mi * 16 + lr) * 32 + kg * 8];
    #pragma unroll
    for (int ni = 0; ni < 4; ni++)
      bfr[ni] = *(const short8*)&Bs[(wc * 64 + ni * 16 + lr) * 32 + kg * 8];
    #pragma unroll
    for (int mi = 0; mi < 4; mi++)
      #pragma unroll
      for (int ni = 0; ni < 4; ni++)
        acc[mi][ni] = __builtin_amdgcn_mfma_f32_16x16x32_bf16(af[mi], bfr[ni], acc[mi][ni], 0, 0, 0);
  }

  #pragma unroll
  for (int mi = 0; mi < 4; mi++)
    #pragma unroll
    for (int ni = 0; ni < 4; ni++){
      int n = n0 + wc * 64 + ni * 16 + lr;
      int mb = m0 + wr * 64 + mi * 16 + kg * 4;
      #pragma unroll
      for (int j = 0; j < 4; j++)
        Cc[(size_t)(mb + j) * N + n] = f2bf(acc[mi][ni][j]);
    }
}

// ================= 256x256 2-phase counted-vmcnt GEMM, writes vt (C,B,T) =================
// A: (65536 x 1024) bf16, Bt: (1024 x 1024) bf16, K=1024 fixed.
// LDS: A[slot][kh][256][32] at 0, B[slot][kh][256][32] at 65536; rows 64B.
// Swizzle involution on in-unit byte offset: off ^= ((off>>7)&3)<<4 (verified conflict-free r4).
// Fragment reads are INLINE-ASM ds_read_b128: opaque to the compiler's memory legalizer,
// so it cannot insert conservative vmcnt(0) drains for DMA-written LDS aliasing.
#define SWZ(x) ((x) ^ ((((x) >> 7) & 3) << 4))

#define STAGE_A(kt, kh) { \
  int d_ = wv * 1024 + ln * 16; int o_ = SWZ(d_); \
  gload16(Ag + (size_t)(m0 + (o_ >> 6)) * 1024 + (kt) * 64 + (kh) * 32 + ((o_ >> 4) & 3) * 8, \
          ldsc + ((kt) & 1) * 32768 + (kh) * 16384 + wv * 1024); \
  d_ += 8192; o_ = SWZ(d_); \
  gload16(Ag + (size_t)(m0 + (o_ >> 6)) * 1024 + (kt) * 64 + (kh) * 32 + ((o_ >> 4) & 3) * 8, \
          ldsc + ((kt) & 1) * 32768 + (kh) * 16384 + 8192 + wv * 1024); }

#define STAGE_B(kt, kh) { \
  int d_ = wv * 1024 + ln * 16; int o_ = SWZ(d_); \
  gload16(Bg + (size_t)(n0 + (o_ >> 6)) * 1024 + (kt) * 64 + (kh) * 32 + ((o_ >> 4) & 3) * 8, \
          ldsc + 65536 + ((kt) & 1) * 32768 + (kh) * 16384 + wv * 1024); \
  d_ += 8192; o_ = SWZ(d_); \
  gload16(Bg + (size_t)(n0 + (o_ >> 6)) * 1024 + (kt) * 64 + (kh) * 32 + ((o_ >> 4) & 3) * 8, \
          ldsc + 65536 + ((kt) & 1) * 32768 + (kh) * 16384 + 8192 + wv * 1024); }

__global__ __launch_bounds__(512, 2) void gemm256_vt(
    const unsigned short* __restrict__ Ag,  // 65536 x 1024
    const unsigned short* __restrict__ Bg,  // 1024 x 1024 (Bt)
    unsigned short* __restrict__ vt)        // (C, B, T)
{
  extern __shared__ char ldsc[];            // 131072 B
  typedef __attribute__((address_space(3))) char lds_char;
  lds_char* lds3 = (lds_char*)ldsc;
  const int tid = threadIdx.x;
  const int ln  = tid & 63;
  const int wv  = tid >> 6;                 // 8 waves
  const int wr  = wv >> 2;                  // 2 M-waves (128 rows each)
  const int wc  = wv & 3;                   // 4 N-waves (64 cols each)
  const int lr  = ln & 15, kg = ln >> 4;
  const int m0  = blockIdx.y * 256;
  const int n0  = blockIdx.x * 256;

  f32x4 acc[8][4];
  #pragma unroll
  for (int mi = 0; mi < 8; mi++)
    #pragma unroll
    for (int ni = 0; ni < 4; ni++)
      acc[mi][ni] = (f32x4){0.f, 0.f, 0.f, 0.f};

  // prologue: stage tile 0 into slot 0 (8 loads in flight)
  STAGE_A(0, 0); STAGE_A(0, 1); STAGE_B(0, 0); STAGE_B(0, 1);

  short8 af[2][8], bf2[2][4];

  #pragma unroll 1
  for (int t = 0; t < 16; ++t){
    const int S = t & 1;
    if (t < 15){
      // issue next tile's 8 loads into the other slot, keep them in flight
      STAGE_A(t + 1, 0); STAGE_A(t + 1, 1); STAGE_B(t + 1, 0); STAGE_B(t + 1, 1);
      __builtin_amdgcn_sched_barrier(0);
      asm volatile("s_waitcnt vmcnt(8)");   // current tile's 8 landed; next 8 in flight
      __builtin_amdgcn_sched_barrier(0);
    } else {
      __builtin_amdgcn_sched_barrier(0);
      asm volatile("s_waitcnt vmcnt(0)");
      __builtin_amdgcn_sched_barrier(0);
    }
    __builtin_amdgcn_s_barrier();           // all waves' DMAs for this slot landed
    __builtin_amdgcn_sched_barrier(0);

    // issue all 24 fragment reads (12 per K-half), opaque asm
    #pragma unroll
    for (int kk = 0; kk < 2; ++kk){
      #pragma unroll
      for (int mi = 0; mi < 8; mi++){
        int off = S * 32768 + kk * 16384 + (wr * 128 + mi * 16 + lr) * 64 + kg * 16;
        unsigned a_ = (unsigned)(size_t)(lds3 + SWZ(off));
        asm volatile("ds_read_b128 %0, %1" : "=v"(af[kk][mi]) : "v"(a_));
      }
      #pragma unroll
      for (int ni = 0; ni < 4; ni++){
        int off = 65536 + S * 32768 + kk * 16384 + (wc * 64 + ni * 16 + lr) * 64 + kg * 16;
        unsigned a_ = (unsigned)(size_t)(lds3 + SWZ(off));
        asm volatile("ds_read_b128 %0, %1" : "=v"(bf2[kk][ni]) : "v"(a_));
      }
    }

    asm volatile("s_waitcnt lgkmcnt(12)");  // K-half 0's reads done; half 1 still in flight
    __builtin_amdgcn_sched_barrier(0);
    __builtin_amdgcn_s_setprio(1);
    #pragma unroll
    for (int mi = 0; mi < 8; mi++)
      #pragma unroll
      for (int ni = 0; ni < 4; ni++)
        acc[mi][ni] = __builtin_amdgcn_mfma_f32_16x16x32_bf16(af[0][mi], bf2[0][ni], acc[mi][ni], 0, 0, 0);
    __builtin_amdgcn_s_setprio(0);

    asm volatile("s_waitcnt lgkmcnt(0)");
    __builtin_amdgcn_sched_barrier(0);
    __builtin_amdgcn_s_setprio(1);
    #pragma unroll
    for (int mi = 0; mi < 8; mi++)
      #pragma unroll
      for (int ni = 0; ni < 4; ni++)
        acc[mi][ni] = __builtin_amdgcn_mfma_f32_16x16x32_bf16(af[1][mi], bf2[1][ni], acc[mi][ni], 0, 0, 0);
    __builtin_amdgcn_s_setprio(0);
    __builtin_amdgcn_sched_barrier(0);
    __builtin_amdgcn_s_barrier();           // readers done before next iter's DMAs overwrite
  }

  // epilogue: vt[(n*B + b)*T + t], m = b*512 + t   (verified r4)
  #pragma unroll
  for (int mi = 0; mi < 8; mi++)
    #pragma unroll
    for (int ni = 0; ni < 4; ni++){
      int n  = n0 + wc * 64 + ni * 16 + lr;
      int mb = m0 + wr * 128 + mi * 16 + kg * 4;
      int bb = mb >> 9, t = mb & 511;
      ushort4 o;
      o.x = f2bf(acc[mi][ni][0]); o.y = f2bf(acc[mi][ni][1]);
      o.z = f2bf(acc[mi][ni][2]); o.w = f2bf(acc[mi][ni][3]);
      *(ushort4*)&vt[((size_t)n * B_ + bb) * T_ + t] = o;
    }
}

// ---------------- Toeplitz band table: band[c][d32][i][j] = z_c[32*d32 + i - j] ----------------
__global__ void band_prep(const float* __restrict__ pw, const float* __restrict__ line,
                          unsigned short* __restrict__ band){
  const int c = blockIdx.x, d32 = blockIdx.y;
  const float p = pw[c];
  const float e = 2.0f + 100.0f / (1.0f + expf(-p));
  const int tid = threadIdx.x;
  for (int idx = tid; idx < 1280; idx += 256){
    int i = idx / 40, j = idx - i * 40;
    int k = d32 * 32 + i - j;
    float z = 0.f;
    if (j < 32 && k >= 0 && k < T_){
      float lv = line[k];
      z = (lv > 0.f) ? expf(e * logf(lv)) : 0.f;
    }
    band[((size_t)c * 16 + d32) * 1280 + idx] = f2bf(z);
  }
}

// ---------------- conv via MFMA: per (c, t-tile 128) block, Y[t][b] = sum_s z[t-s] v[b][s] ----
__global__ __launch_bounds__(256) void conv_mfma(
    const unsigned short* __restrict__ vt,    // (C, B, T) bf16
    const unsigned short* __restrict__ band,  // (C, 16, 32, 40) bf16
    const float* __restrict__ gain,           // (1,1,C)
    unsigned short* __restrict__ Ybf)         // (C, B, T) bf16, gain+relu applied
{
  __shared__ short Bs[128 * 32];      // v tile: 128 b x 32 s
  __shared__ short Ab[16 * 1280];     // up to 16 Toeplitz bands (40KB)
  const int c   = blockIdx.x;
  const int t0  = blockIdx.y << 7;
  const int tid = threadIdx.x, lane = tid & 63, wave = tid >> 6;
  const int wr = wave >> 1, wc = wave & 1, lr = lane & 15, kg = lane >> 4;
  const int K  = t0 + 128;            // causal: s < t0+128
  const int nb = (t0 >> 5) + 4;       // bands d32 = 0..nb-1

  // stage all needed bands once (linear gload16)
  {
    const unsigned short* src = band + (size_t)c * (16 * 1280);
    const int nch = nb * 160;                      // 16B chunks
    for (int q0 = 0; q0 < nch; q0 += 256){
      int q = q0 + tid;
      char* dst = (char*)Ab + q0 * 16 + wave * 1024;   // wave-uniform
      if (q < nch) gload16(src + (size_t)q * 8, dst);
    }
  }

  f32x4 acc[4][4];
  #pragma unroll
  for (int mi = 0; mi < 4; mi++)
    #pragma unroll
    for (int ni = 0; ni < 4; ni++)
      acc[mi][ni] = (f32x4){0.f, 0.f, 0.f, 0.f};

  const int r1 = tid >> 2, ch1 = tid & 3;
  char* bbase = (char*)Bs + (tid & ~63) * 16;
  const size_t vbase = (size_t)c * B_ * T_;

  for (int k0 = 0; k0 < K; k0 += 32){
    __syncthreads();
    gload16(vt + vbase + (size_t)r1 * T_        + k0 + ch1 * 8, bbase);
    gload16(vt + vbase + (size_t)(64 + r1) * T_ + k0 + ch1 * 8, bbase + 4096);
    __syncthreads();

    short8 bfr[4];
    #pragma unroll
    for (int ni = 0; ni < 4; ni++)
      bfr[ni] = *(const short8*)&Bs[(wc * 64 + ni * 16 + lr) * 32 + kg * 8];

    const int dbase = ((t0 - k0) >> 5) + wr * 2;
    #pragma unroll
    for (int mi = 0; mi < 4; mi++){
      const int d32 = dbase + (mi >> 1);         // wave-uniform per mi
      if (d32 >= 0){
        const int i = ((mi & 1) << 4) + lr;      // row within band
        short8 af = *(const short8*)&Ab[d32 * 1280 + i * 40 + kg * 8];
        #pragma unroll
        for (int ni = 0; ni < 4; ni++)
          acc[mi][ni] = __builtin_amdgcn_mfma_f32_16x16x32_bf16(af, bfr[ni], acc[mi][ni], 0, 0, 0);
      }
    }
  }

  const float g = gain[c];
  #pragma unroll
  for (int mi = 0; mi < 4; mi++)
    #pragma unroll
    for (int ni = 0; ni < 4; ni++){
      int t = t0 + wr * 64 + mi * 16 + kg * 4;   // 4 consecutive t (j)
      int b = wc * 64 + ni * 16 + lr;
      ushort4 o;
      o.x = f2bf(fmaxf(acc[mi][ni][0] * g, 0.f));
      o.y = f2bf(fmaxf(acc[mi][ni][1] * g, 0.f));
      o.z = f2bf(fmaxf(acc[mi][ni][2] * g, 0.f));
      o.w = f2bf(fmaxf(acc[mi][ni][3] * g, 0.f));
      *(ushort4*)&Ybf[((size_t)c * B_ + b) * T_ + t] = o;
    }
}

// ---------------- final: (C,B,T) bf16 -> (B,T,C) f32 ----------------
__global__ __launch_bounds__(256) void final_out(const unsigned short* __restrict__ Ybf,
                                                 float* __restrict__ out){
  __shared__ unsigned short tile[64][72];
  const int c0 = blockIdx.x * 64;
  const int t0 = blockIdx.y * 64;
  const int b  = blockIdx.z;
  const int tid = threadIdx.x;
  const int cr = tid >> 4;
  const int t4 = (tid & 15) * 4;
  for (int q = 0; q < 64; q += 16){
    ushort4 u = *(const ushort4*)&Ybf[((size_t)(c0 + cr + q) * B_ + b) * T_ + t0 + t4];
    *(ushort4*)&tile[cr + q][t4] = u;
  }
  __syncthreads();
  const int tr = tid >> 4;
  const int c4 = (tid & 15) * 4;
  for (int q = 0; q < 64; q += 16){
    int t = tr + q;
    float4 o;
    o.x = __uint_as_float((unsigned)tile[c4 + 0][t] << 16);
    o.y = __uint_as_float((unsigned)tile[c4 + 1][t] << 16);
    o.z = __uint_as_float((unsigned)tile[c4 + 2][t] << 16);
    o.w = __uint_as_float((unsigned)tile[c4 + 3][t] << 16);
    *(float4*)&out[((size_t)b * T_ + t0 + t) * C_ + c0 + c4] = o;
  }
}

extern "C" void kernel_launch(void* const* d_in, const int* in_sizes, int n_in,
                              void* d_out, int out_size, void* d_ws, size_t ws_size,
                              hipStream_t stream)
{
  (void)in_sizes; (void)n_in; (void)out_size; (void)ws_size;
  const float* x    = (const float*)d_in[0];
  const float* Wp   = (const float*)d_in[1];
  const float* Wv   = (const float*)d_in[2];
  const float* gain = (const float*)d_in[3];
  const float* pw   = (const float*)d_in[4];
  const float* line = (const float*)d_in[5];
  float* out = (float*)d_out;

  // ws: [Ybf 128MB][WpT 2MB][Wv_bf 2MB][W_f 2MB]
  char* ws = (char*)d_ws;
  unsigned short* Ybf   = (unsigned short*)ws;
  unsigned short* WpT   = (unsigned short*)(ws + 134217728);
  unsigned short* Wv_bf = (unsigned short*)(ws + 134217728 + 2097152);
  unsigned short* W_f   = (unsigned short*)(ws + 134217728 + 2 * 2097152);
  // d_out (256MB f32) reused as scratch with ping-pong lifetimes:
  unsigned short* x_bf  = (unsigned short*)d_out;                    // lower 128MB (dead after GEMM)
  unsigned short* vt    = (unsigned short*)d_out + 67108864;         // upper 128MB (dead after conv)
  unsigned short* bandp = (unsigned short*)d_out;                    // lower 40MB, written AFTER GEMM

  // weights
  cast_f32_bf16<<<256, 256, 0, stream>>>(Wv, Wv_bf, (long)C_ * C_);
  transpose_cast<<<dim3(32, 32), dim3(32, 8), 0, stream>>>(Wp, WpT);
  gemm_bt_bf16<<<dim3(8, 8), 256, 0, stream>>>(Wv_bf, WpT, W_f, C_, C_, C_);
  // x -> bf16
  cast_f32_bf16<<<2048, 256, 0, stream>>>(x, x_bf, (long)B_ * T_ * C_);
  // v = x @ W_f^T, written directly as (C,B,T); 256^2 2-phase counted-vmcnt kernel
  gemm256_vt<<<dim3(4, 256), 512, 131072, stream>>>(x_bf, W_f, vt);
  // Toeplitz bands (overwrites x_bf region — dead now)
  band_prep<<<dim3(1024, 16), 256, 0, stream>>>(pw, line, bandp);
  // conv + gain + relu -> Ybf (C,B,T); round-2 measured-best grid (c fastest)
  conv_mfma<<<dim3(1024, 4), 256, 0, stream>>>(vt, bandp, gain, Ybf);
  // transpose to (B,T,C) f32
  final_out<<<dim3(16, 8, 128), 256, 0, stream>>>(Ybf, out);
}